// Round 1
// baseline (341.423 us; speedup 1.0000x reference)
//
#include <hip/hip_runtime.h>

#define OUT_H 7
#define OUT_W 7
#define SRATIO 2

__global__ __launch_bounds__(256) void roialign_fwd(
    const float* __restrict__ feat,   // (N, C, H, W)
    const float* __restrict__ rois,   // (B, 5) [bidx, x1, y1, x2, y2]
    float* __restrict__ out,          // (B, C, OUT_H, OUT_W)
    int total, int C, int H, int W)
{
    int idx = blockIdx.x * blockDim.x + threadIdx.x;
    if (idx >= total) return;

    const float spatial_scale = 0.25f;

    int pw = idx % OUT_W;
    int ph = (idx / OUT_W) % OUT_H;
    int c  = (idx / (OUT_W * OUT_H)) % C;
    int b  = idx / (OUT_W * OUT_H * C);

    const float* r = rois + (size_t)b * 5;
    int   bi  = (int)r[0];
    float rx1 = r[1] * spatial_scale;
    float ry1 = r[2] * spatial_scale;
    float rx2 = r[3] * spatial_scale;
    float ry2 = r[4] * spatial_scale;

    float roi_w = fmaxf(rx2 - rx1, 1.0f);
    float roi_h = fmaxf(ry2 - ry1, 1.0f);
    float bin_w = roi_w / (float)OUT_W;
    float bin_h = roi_h / (float)OUT_H;

    const float* fptr = feat + ((size_t)bi * C + c) * (size_t)(H * W);

    float acc = 0.0f;
    #pragma unroll
    for (int iy = 0; iy < SRATIO; ++iy) {
        float yy = ry1 + ((float)ph + ((float)iy + 0.5f) / (float)SRATIO) * bin_h;
        float py = fminf(fmaxf(yy - 0.5f, 0.0f), (float)(H - 1));
        int   y0 = (int)floorf(py);
        int   y1 = min(y0 + 1, H - 1);
        float wy = py - (float)y0;

        #pragma unroll
        for (int ix = 0; ix < SRATIO; ++ix) {
            float xx = rx1 + ((float)pw + ((float)ix + 0.5f) / (float)SRATIO) * bin_w;
            float px = fminf(fmaxf(xx - 0.5f, 0.0f), (float)(W - 1));
            int   x0 = (int)floorf(px);
            int   x1 = min(x0 + 1, W - 1);
            float wx = px - (float)x0;

            float v00 = fptr[y0 * W + x0];
            float v01 = fptr[y0 * W + x1];
            float v10 = fptr[y1 * W + x0];
            float v11 = fptr[y1 * W + x1];

            acc += v00 * (1.0f - wy) * (1.0f - wx)
                 + v01 * (1.0f - wy) * wx
                 + v10 * wy * (1.0f - wx)
                 + v11 * wy * wx;
        }
    }

    out[idx] = acc * (1.0f / (SRATIO * SRATIO));
}

extern "C" void kernel_launch(void* const* d_in, const int* in_sizes, int n_in,
                              void* d_out, int out_size, void* d_ws, size_t ws_size,
                              hipStream_t stream) {
    const float* feat = (const float*)d_in[0];
    const float* rois = (const float*)d_in[1];
    float* out = (float*)d_out;

    const int C = 256, H = 200, W = 200;
    int total = out_size;  // B * C * OUT_H * OUT_W

    int block = 256;
    int grid = (total + block - 1) / block;
    roialign_fwd<<<grid, block, 0, stream>>>(feat, rois, out, total, C, H, W);
}